// Round 7
// baseline (297.109 us; speedup 1.0000x reference)
//
#include <hip/hip_runtime.h>
#include <stdint.h>

#define N_TOTAL 21840
#define NA      21888          // N_TOTAL rounded up to multiple of 64
#define W_MAX   342            // ceil(21840/64)
#define NA2     22528          // 352 words: padded diag/band rows (no clamps)
#define TOT_ENT 3753792u       // 64 * (342*343/2)  triangular dense capacity
#define NMS_TH  0.3f
#define FINAL_TH 0.5f
#define NSLICE  8              // rank range-split factor
#define SCAN_T  768            // scan block: 1 scanner wave + 11 pusher waves
#define NPUSH   11             // pusher wave count (SCAN_T/64 - 1)
#define PLANES  704            // NPUSH*64 pusher lanes
#define GRP     3              // words per scan group (fits VGPR budget!)
#define NBAND   5              // 2*GRP-1 transposed band arrays
#define GMAX    114            // max groups = ceil(342/3)
#define DEPTH   4              // pusher entry slots per word (covers tw~2400)

struct Inputs { const float* cls[6]; const float* reg[6]; };

// Raw barrier: drains LDS (lgkmcnt) but NOT vmem (vmcnt).
__device__ __forceinline__ void block_bar() {
  asm volatile("s_waitcnt lgkmcnt(0)\n\ts_barrier" ::: "memory");
}

// Dense per-word base: word w owns 64*(342-w) entry slots (triangular).
__device__ __forceinline__ unsigned wbase_u(unsigned w) {
  return 64u * (342u * w - (w * (w - 1u)) / 2u);
}

// ---------------------------------------------------------------- decode ----
__global__ void decode_kernel(Inputs in,
                              float* __restrict__ dx1, float* __restrict__ dy1,
                              float* __restrict__ dx2, float* __restrict__ dy2,
                              float* __restrict__ dsc,
                              unsigned long long* __restrict__ ckey,
                              unsigned int* __restrict__ Mc,
                              unsigned int* __restrict__ rank32,
                              unsigned int* __restrict__ wcnt,
                              float* __restrict__ out) {
#pragma clang fp contract(off)
  int gid = blockIdx.x * blockDim.x + threadIdx.x;
  if (gid >= N_TOTAL) return;

  rank32[gid] = 0u;                       // zeroed ahead of rank_kernel
  wcnt[gid] = 0u;                         // per-word dense-entry counters
  if (gid < NA - N_TOTAL) wcnt[N_TOTAL + gid] = 0u;   // tail

  int sc, local;
  if      (gid < 16384) { sc = 0; local = gid;         }
  else if (gid < 20480) { sc = 1; local = gid - 16384; }
  else if (gid < 21504) { sc = 2; local = gid - 20480; }
  else if (gid < 21760) { sc = 3; local = gid - 21504; }
  else if (gid < 21824) { sc = 4; local = gid - 21760; }
  else                  { sc = 5; local = gid - 21824; }

  const int Wd     = 128 >> sc;
  const int stride = 4 << sc;
  const int HW     = Wd * Wd;
  const int x = local & (Wd - 1);
  const int y = local >> (7 - sc);

  const float* cls = in.cls[sc];
  const float* reg = in.reg[sc];

  float c0 = cls[local];
  float c1 = cls[HW + local];
  float m  = fmaxf(c0, c1);
  float e0 = expf(c0 - m);
  float e1 = expf(c1 - m);
  float prob = e1 / (e0 + e1);

  float l0 = reg[local];
  float l1 = reg[HW + local];
  float l2 = reg[2 * HW + local];
  float l3 = reg[3 * HW + local];

  float sF  = (float)stride;
  float pcx = 0.5f * sF + (float)x * sF;
  float pcy = 0.5f * sF + (float)y * sF;
  float pwh = sF * 4.0f;

  float cx = pcx + ((l0 * 0.1f) * pwh);
  float cy = pcy + ((l1 * 0.1f) * pwh);
  float w  = pwh * expf(l2 * 0.2f);
  float h  = pwh * expf(l3 * 0.2f);
  float x1 = cx - w * 0.5f;
  float y1 = cy - h * 0.5f;
  float x2 = x1 + w;
  float y2 = y1 + h;

  dx1[gid] = x1; dy1[gid] = y1; dx2[gid] = x2; dy2[gid] = y2; dsc[gid] = prob;

  // zero the output row; scan_kernel scatters kept rows afterwards
  out[gid * 5 + 0] = 0.0f;
  out[gid * 5 + 1] = 0.0f;
  out[gid * 5 + 2] = 0.0f;
  out[gid * 5 + 3] = 0.0f;
  out[gid * 5 + 4] = 0.0f;

  // Only boxes with score > FINAL_TH can affect the output.
  if (prob > FINAL_TH) {
    unsigned int pos = atomicAdd(Mc, 1u);
    ckey[pos] = ((unsigned long long)__float_as_uint(prob) << 32) |
                (unsigned int)(~(unsigned int)gid);
  }
}

// ---------------------------------------------------------------- rank ------
__global__ void __launch_bounds__(256)
rank_kernel(const unsigned long long* __restrict__ ckey,
            const unsigned int* __restrict__ Mc,
            const float* __restrict__ dx1, const float* __restrict__ dy1,
            const float* __restrict__ dx2, const float* __restrict__ dy2,
            float* __restrict__ sx1, float* __restrict__ sy1,
            float* __restrict__ sx2, float* __restrict__ sy2,
            unsigned int* __restrict__ sorig,
            unsigned int* __restrict__ rank32) {
  __shared__ unsigned long long tile[256];
  const unsigned int M = *Mc;
  if (blockIdx.x * 256u >= M) return;          // uniform per block
  const int t = (int)threadIdx.x;
  const int p = (int)blockIdx.x * 256 + t;
  unsigned long long mykey = (p < (int)M) ? ckey[p] : 0ull;
  const int S  = (int)((M + NSLICE - 1) / NSLICE);
  const int lo = (int)blockIdx.y * S;
  const int hi = min((int)M, lo + S);
  int partial = 0;
  const int nt = (hi > lo) ? ((hi - lo + 255) >> 8) : 0;
  for (int ti = 0; ti < nt; ++ti) {
    int j = lo + ti * 256 + t;
    tile[t] = (j < hi) ? ckey[j] : 0ull;       // 0 never > any real key
    __syncthreads();
#pragma unroll 8
    for (int q = 0; q < 256; ++q) partial += (tile[q] > mykey) ? 1 : 0;
    __syncthreads();
  }
  if (p < (int)M) {
    unsigned int pack = (unsigned int)partial | (1u << 24);
    unsigned int old  = atomicAdd(&rank32[p], pack);
    unsigned int newv = old + pack;
    if ((newv >> 24) == NSLICE) {              // last slice to land scatters
      int r = (int)(newv & 0xFFFFFF);
      unsigned int orig = ~(unsigned int)(mykey & 0xffffffffull);
      sx1[r] = dx1[orig];
      sy1[r] = dy1[orig];
      sx2[r] = dx2[orig];
      sy2[r] = dy2[orig];
      sorig[r] = orig;
    }
  }
}

// ---------------------------------------------------------------- pairs -----
// Structure for GRP=3 grouped scan:
//   diag[r]        = FULL symmetric in-word neighborhood (masked at use)
//   bandT[d-1][r]  = boxes of word (rw-d) overlapping box r, d = 1..5
//                    (materialized iff group(rw-d) >= group(rw)-1)
//   Dense CSR      = per SOURCE WORD ranges, entry = bits + (srcLane<<9)|cw,
//                    group(cw) >= group(rw)+2 ONLY.
// Block-aggregated append (one global atomicAdd per block).
__global__ void __launch_bounds__(1024)
pairs_kernel(const float* __restrict__ sx1, const float* __restrict__ sy1,
             const float* __restrict__ sx2, const float* __restrict__ sy2,
             const unsigned int* __restrict__ Mc,
             unsigned long long* __restrict__ diag,
             unsigned long long* __restrict__ bandT,
             unsigned int* __restrict__ wcnt,
             unsigned short* __restrict__ rlMeta,
             unsigned long long* __restrict__ rlBits) {
#pragma clang fp contract(off)
  const int M = (int)*Mc;
  const int W = (M + 63) >> 6;
  const int rw = (int)blockIdx.y;
  const int cwg = (int)blockIdx.x << 4;
  if (rw >= W || cwg >= W || cwg + 20 < rw) return;   // need cw >= rw-5

  const int t = (int)threadIdx.x;
  const int g = t >> 6, l = t & 63;
  const int cw = cwg + g;

  __shared__ float cx1[1024], cy1[1024], cx2[1024], cy2[1024], car[1024];
  __shared__ unsigned wvcnt[16], wvbase[16];
  {
    int c = (cw << 6) + l;
    if (cw < W && c < M) {
      float a = sx1[c], b = sy1[c], d = sx2[c], e = sy2[c];
      cx1[t] = a; cy1[t] = b; cx2[t] = d; cy2[t] = e;
      car[t] = (d - a + 1.0f) * (e - b + 1.0f);
    }
  }
  __syncthreads();

  const int rwg = rw / 3, cg = cw / 3;
  const bool inW    = (cw < W);
  const bool isDiag = inW && (cw == rw);
  const bool isBand = inW && (cw < rw) && (cg >= rwg - 1);   // d <= 5
  const bool isCsr  = inW && (cg >= rwg + 2);
  const bool any    = isDiag || isBand || isCsr;

  const int r = (rw << 6) + l;
  unsigned long long bits = 0ull;
  if (any && r < M) {
    float ax1 = sx1[r], ay1 = sy1[r], ax2 = sx2[r], ay2 = sy2[r];
    float aarea = (ax2 - ax1 + 1.0f) * (ay2 - ay1 + 1.0f);
    const int cmax = min(64, M - (cw << 6));
    const int sb = g << 6;
    for (int cc = 0; cc < cmax; ++cc) {
      float xx1 = fmaxf(ax1, cx1[sb + cc]);
      float yy1 = fmaxf(ay1, cy1[sb + cc]);
      float xx2 = fminf(ax2, cx2[sb + cc]);
      float yy2 = fminf(ay2, cy2[sb + cc]);
      float ww = fmaxf(xx2 - xx1 + 1.0f, 0.0f);
      float hh = fmaxf(yy2 - yy1 + 1.0f, 0.0f);
      float inter = ww * hh;
      float iou = inter / (aarea + car[sb + cc] - inter);
      if (iou > NMS_TH) bits |= (1ull << cc);
    }
  }
  if (isDiag)      diag[r] = bits;
  else if (isBand) bandT[(size_t)(rw - cw - 1) * NA2 + r] = bits;

  // CSR block-aggregated append
  unsigned long long ball = 0ull;
  unsigned myrank = 0u;
  {
    bool mine = isCsr && (bits != 0ull);
    ball = __ballot(mine);
    myrank = (unsigned)__popcll(ball & ((1ull << l) - 1ull));
    if (l == 0) wvcnt[g] = (unsigned)__popcll(ball);
  }
  __syncthreads();
  if (t == 0) {
    unsigned tot = 0u;
    unsigned pre[16];
#pragma unroll
    for (int i = 0; i < 16; ++i) { pre[i] = tot; tot += wvcnt[i]; }
    unsigned base = (tot != 0u) ? atomicAdd(&wcnt[rw], tot) : 0u;
#pragma unroll
    for (int i = 0; i < 16; ++i) wvbase[i] = base + pre[i];
  }
  __syncthreads();
  if (isCsr && bits != 0ull) {
    unsigned slot = wbase_u((unsigned)rw) + wvbase[g] + myrank;
    rlMeta[slot] = (unsigned short)(((unsigned)l << 9) | (unsigned)cw);
    rlBits[slot] = bits;
  }
}

// ---------------------------------------------------------------- scan ------
// Decoupled scan (sflag / per-group gdone protocol, verified R4/R6), GRP=3.
// R6 post-mortem: VGPR_Count=72 proved the GRP=4 double-buffers (104+ VGPRs
// of u64 state vs the 768-thread ~170-VGPR cap) were DEMOTED by the register
// allocator — "prefetched" bands were re-loaded from L2 at use, ~15-25 load
// latencies on the scanner chain per group, identical across R2/R4/R6 (the
// invariant 99 µs). GRP=3 shrinks state to ~140 VGPR so the ping-pong
// buffers genuinely live in registers; 2x-unrolled loops avoid rotation
// copies; diag/bandT padded to NA2 words so no v<W clamps are needed
// (reads past W are in-bounds garbage, unused: kc forced 0 by v<W guard).
// Pusher: DEPTH=4 static slots cover tw_max (~2400) — no tail loads.
__global__ void __launch_bounds__(SCAN_T)
scan_kernel(const unsigned long long* __restrict__ diag,
            const unsigned long long* __restrict__ bandT,
            const unsigned int* __restrict__ wcnt,
            const unsigned short* __restrict__ rlMeta,
            const unsigned long long* __restrict__ rlBits,
            const unsigned int* __restrict__ sorig,
            const unsigned int* __restrict__ Mc,
            const float* __restrict__ dx1, const float* __restrict__ dy1,
            const float* __restrict__ dx2, const float* __restrict__ dy2,
            const float* __restrict__ dsc,
            float* __restrict__ out) {
  __shared__ unsigned long long sup[W_MAX];
  __shared__ unsigned long long kmls[W_MAX];
  __shared__ unsigned lds_wcnt[W_MAX];  // per-word entry counts (staged once)
  __shared__ unsigned gdone[GMAX];      // per-group pusher completions
  __shared__ volatile unsigned sflag;   // groups published by scanner
  const int t = (int)threadIdx.x;
  const int g = t >> 6, l = t & 63;
  const int M = (int)*Mc;
  const int W = (M + 63) >> 6;
  const int NS = (W + 2) / 3;

  for (int i = t; i < W_MAX; i += SCAN_T) {
    sup[i] = 0ull; kmls[i] = 0ull; lds_wcnt[i] = wcnt[i];
  }
  for (int i = t; i < GMAX; i += SCAN_T) gdone[i] = 0u;
  if (t == 0) sflag = 0u;
  block_bar();

  if (g == 0) {
    // -------- scanner wave (critical path) --------
    __builtin_amdgcn_s_setprio(1);
    const unsigned long long lowm = (1ull << l) - 1ull;
    // ping-pong buffers: A = even groups, B = odd groups (no rotation movs)
    unsigned long long dA[3], dB[3];
    unsigned long long bA_[3][NBAND], bB_[3][NBAND];   // d <= i+3 used
    unsigned long long kp[3] = {0ull, 0ull, 0ull};

#define SCAN_PROLOAD(DC_, BC_, GS_)                                         \
    { _Pragma("unroll")                                                     \
      for (int i = 0; i < 3; ++i) {                                         \
        const int v_ = (GS_) * 3 + i;                                       \
        DC_[i] = diag[(v_ << 6) + l];                                       \
        _Pragma("unroll")                                                   \
        for (int d = 1; d <= NBAND; ++d)                                    \
          if (d <= i + 3)                                                   \
            BC_[i][d - 1] = bandT[(size_t)(d - 1) * NA2 + (v_ << 6) + l];   \
      } }

    SCAN_PROLOAD(dA, bA_, 0)
    SCAN_PROLOAD(dB, bB_, 1)

#define SCAN_STEP(DC_, BC_, S_)                                             \
    { const int s_ = (S_);                                                  \
      const int v0_ = s_ * 3;                                               \
      unsigned long long accp[3];                                           \
      _Pragma("unroll")                                                     \
      for (int i = 0; i < 3; ++i) {                                         \
        unsigned long long a = 0ull;                                        \
        _Pragma("unroll")                                                   \
        for (int d = 1; d <= NBAND; ++d)                                    \
          if (d <= i + 3 && d > i) a |= (BC_[i][d - 1] & kp[i - d + 3]);    \
        accp[i] = a;                                                        \
      }                                                                     \
      if (s_ >= 2) {                                                        \
        while (*(volatile unsigned*)&gdone[s_ - 2] < (unsigned)NPUSH) {}    \
        asm volatile("" ::: "memory");                                      \
      }                                                                     \
      unsigned long long sv[3];                                             \
      _Pragma("unroll")                                                     \
      for (int i = 0; i < 3; ++i)                                           \
        sv[i] = (v0_ + i < W) ? sup[v0_ + i] : 0ull;                        \
      unsigned long long kc[3];                                             \
      _Pragma("unroll")                                                     \
      for (int i = 0; i < 3; ++i) {                                         \
        const int v_ = v0_ + i;                                             \
        unsigned long long kept = 0ull;                                     \
        if (v_ < W) {                                                       \
          unsigned long long acc = accp[i];                                 \
          _Pragma("unroll")                                                 \
          for (int d = 1; d <= 2; ++d)                                      \
            if (d <= i) acc |= (BC_[i][d - 1] & kc[i - d]);                 \
          unsigned long long incoming = __ballot(acc != 0ull);              \
          const int n_ = min(64, M - (v_ << 6));                            \
          unsigned long long wm =                                           \
              (n_ >= 64) ? ~0ull : ((1ull << n_) - 1ull);                   \
          unsigned long long pend = (~(sv[i] | incoming)) & wm;             \
          const unsigned long long dv = DC_[i] & lowm;                      \
          unsigned long long dead = ~pend, und = pend;                      \
          while (und) {                                                     \
            unsigned long long bS = __ballot((dv & kept) != 0ull) & und;    \
            unsigned long long bK = __ballot((dv & ~dead) == 0ull) & und;   \
            kept |= bK; dead |= bS; und &= ~(bK | bS);                      \
          }                                                                 \
          if (l == i) kmls[v_] = kept;                                      \
        }                                                                   \
        kc[i] = kept;                                                       \
      }                                                                     \
      asm volatile("s_waitcnt lgkmcnt(0)" ::: "memory");                    \
      if (l == 0) sflag = (unsigned)(s_ + 1);                               \
      SCAN_PROLOAD(DC_, BC_, s_ + 2)  /* overwrite dead buffer with s+2 */  \
      _Pragma("unroll")                                                     \
      for (int i = 0; i < 3; ++i) kp[i] = kc[i];                            \
    }

    for (int s = 0; s < NS; s += 2) {
      SCAN_STEP(dA, bA_, s)
      if (s + 1 < NS) SCAN_STEP(dB, bB_, s + 1)
    }
#undef SCAN_STEP
#undef SCAN_PROLOAD
    __builtin_amdgcn_s_setprio(0);
  } else {
    // -------- pusher lanes: dense ranges, DEPTH-4 static ping-pong --------
    const int p = (g - 1) * 64 + l;              // 0..703
    unsigned mA[3][DEPTH], mB[3][DEPTH];
    unsigned long long bA[3][DEPTH], bB[3][DEPTH];

#define PUSH_LOAD4(MX_, BX_, GS_)                                           \
    { _Pragma("unroll")                                                     \
      for (int i = 0; i < 3; ++i) {                                         \
        int v_ = (GS_) * 3 + i;                                             \
        unsigned vc_ = (v_ < W) ? (unsigned)v_ : 0u;                        \
        unsigned base_ = wbase_u(vc_) + (unsigned)p;                        \
        _Pragma("unroll")                                                   \
        for (int k = 0; k < DEPTH; ++k) {                                   \
          unsigned ii_ = base_ + (unsigned)(k * PLANES);                    \
          if (ii_ >= TOT_ENT) ii_ = 0u;                                     \
          MX_[i][k] = (unsigned)rlMeta[ii_]; BX_[i][k] = rlBits[ii_];       \
        }                                                                   \
      } }

#define PUSH_STEP(MC_, BC2_, S_)                                            \
    { const int s_ = (S_);                                                  \
      while (sflag < (unsigned)(s_ + 1)) __builtin_amdgcn_s_sleep(1);       \
      asm volatile("" ::: "memory");                                        \
      _Pragma("unroll")                                                     \
      for (int i = 0; i < 3; ++i) {                                         \
        const int v_ = s_ * 3 + i;                                          \
        if (v_ < W) {                                                       \
          const unsigned tw_ = lds_wcnt[v_];                                \
          const unsigned long long km_ = kmls[v_];                          \
          if (km_ != 0ull && tw_ != 0u) {                                   \
            _Pragma("unroll")                                               \
            for (int k = 0; k < DEPTH; ++k) {                               \
              if ((unsigned)p + (unsigned)(k * PLANES) < tw_ &&             \
                  ((km_ >> (MC_[i][k] >> 9)) & 1ull))                       \
                atomicOr(&sup[MC_[i][k] & 511u], BC2_[i][k]);               \
            }                                                               \
            if (tw_ > (unsigned)(DEPTH * PLANES)) {   /* safety tail */     \
              unsigned base_ = wbase_u((unsigned)v_);                       \
              for (unsigned ii_ = (unsigned)p + (unsigned)(DEPTH * PLANES); \
                   ii_ < tw_; ii_ += (unsigned)PLANES) {                    \
                unsigned sl_ = base_ + ii_;                                 \
                if (sl_ >= TOT_ENT) sl_ = TOT_ENT - 1u;                     \
                unsigned mm_ = (unsigned)rlMeta[sl_];                       \
                if ((km_ >> (mm_ >> 9)) & 1ull)                             \
                  atomicOr(&sup[mm_ & 511u], rlBits[sl_]);                  \
              }                                                             \
            }                                                               \
          }                                                                 \
        }                                                                   \
      }                                                                     \
      asm volatile("s_waitcnt lgkmcnt(0)" ::: "memory");                    \
      if (l == 0) atomicAdd(&gdone[s_], 1u);                                \
      PUSH_LOAD4(MC_, BC2_, s_ + 2)                                         \
    }

    PUSH_LOAD4(mA, bA, 0)
    PUSH_LOAD4(mB, bB, 1)
    for (int s = 0; s < NS; s += 2) {
      PUSH_STEP(mA, bA, s)
      if (s + 1 < NS) PUSH_STEP(mB, bB, s + 1)
    }
#undef PUSH_STEP
#undef PUSH_LOAD4
  }
  block_bar();

  // scatter kept rows into the (pre-zeroed) output
  for (int i = t; i < (W << 6); i += SCAN_T) {
    if ((kmls[i >> 6] >> (i & 63)) & 1ull) {
      unsigned int orig = sorig[i];
      out[(size_t)orig * 5 + 0] = dx1[orig];
      out[(size_t)orig * 5 + 1] = dy1[orig];
      out[(size_t)orig * 5 + 2] = dx2[orig];
      out[(size_t)orig * 5 + 3] = dy2[orig];
      out[(size_t)orig * 5 + 4] = dsc[orig];
    }
  }
}

// ------------------------------------------------- fallback NMS (tiny ws) ---
__global__ void __launch_bounds__(1024)
nms_kernel(const float* __restrict__ sx1, const float* __restrict__ sy1,
           const float* __restrict__ sx2, const float* __restrict__ sy2,
           const unsigned int* __restrict__ sorig,
           const unsigned int* __restrict__ Mc,
           unsigned int* __restrict__ keepflag) {
#pragma clang fp contract(off)
  __shared__ unsigned long long sup[W_MAX];
  __shared__ unsigned long long inrow[64];
  __shared__ float wx1[64], wy1[64], wx2[64], wy2[64], warea[64];
  __shared__ unsigned long long keptmask_sh;

  const int t = (int)threadIdx.x;
  const int M = (int)*Mc;
  const int W = (M + 63) >> 6;

  for (int i = t; i < W_MAX; i += 1024) sup[i] = 0ull;
  __syncthreads();

  for (int w = 0; w < W; ++w) {
    const int base = w << 6;
    const int n = min(64, M - base);
    if (t < 64) {
      if (t < n) {
        float a = sx1[base + t], b = sy1[base + t];
        float c = sx2[base + t], d = sy2[base + t];
        wx1[t] = a; wy1[t] = b; wx2[t] = c; wy2[t] = d;
        warea[t] = (c - a + 1.0f) * (d - b + 1.0f);
      }
    } else if (t < 128) {
      inrow[t - 64] = 0ull;
    }
    __syncthreads();
    {
      int r = t & 63, seg = t >> 6;
      unsigned long long bits = 0ull;
      if (r < n) {
        float ax1 = wx1[r], ay1 = wy1[r], ax2 = wx2[r], ay2 = wy2[r];
        float aarea = warea[r];
        for (int c = seg * 4; c < seg * 4 + 4; ++c) {
          if (c > r && c < n) {
            float xx1 = fmaxf(ax1, wx1[c]);
            float yy1 = fmaxf(ay1, wy1[c]);
            float xx2 = fminf(ax2, wx2[c]);
            float yy2 = fminf(ay2, wy2[c]);
            float ww = fmaxf(xx2 - xx1 + 1.0f, 0.0f);
            float hh = fmaxf(yy2 - yy1 + 1.0f, 0.0f);
            float inter = ww * hh;
            float iou = inter / (aarea + warea[c] - inter);
            if (iou > NMS_TH) bits |= (1ull << c);
          }
        }
      }
      if (bits) atomicOr(&inrow[r], bits);
    }
    __syncthreads();
    if (t < 64) {
      unsigned long long wordmask = (n >= 64) ? ~0ull : ((1ull << n) - 1ull);
      unsigned long long pending = (~sup[w]) & wordmask;
      unsigned long long kept = 0ull;
      while (pending) {
        int i = __builtin_ctzll(pending);
        kept |= (1ull << i);
        pending &= ~(inrow[i] | (1ull << i));
      }
      if (t == 0) keptmask_sh = kept;
      if (t < n && ((kept >> t) & 1ull)) keepflag[sorig[base + t]] = 1u;
    }
    __syncthreads();
    unsigned long long km = keptmask_sh;
    if (km) {
      int wid = t >> 6, lane = t & 63;
      for (int jw = w + 1 + wid; (jw << 6) < M; jw += 16) {
        int j = (jw << 6) + lane;
        bool supj = false;
        if (j < M) {
          float jx1 = sx1[j], jy1 = sy1[j], jx2 = sx2[j], jy2 = sy2[j];
          float jarea = (jx2 - jx1 + 1.0f) * (jy2 - jy1 + 1.0f);
          unsigned long long mm = km;
          while (mm) {
            int r = __builtin_ctzll(mm);
            mm &= mm - 1ull;
            float xx1 = fmaxf(wx1[r], jx1);
            float yy1 = fmaxf(wy1[r], jy1);
            float xx2 = fminf(wx2[r], jx2);
            float yy2 = fminf(wy2[r], jy2);
            float ww = fmaxf(xx2 - xx1 + 1.0f, 0.0f);
            float hh = fmaxf(yy2 - yy1 + 1.0f, 0.0f);
            float inter = ww * hh;
            float iou = inter / (warea[r] + jarea - inter);
            if (iou > NMS_TH) { supj = true; break; }
          }
        }
        unsigned long long bal = __ballot(supj);
        if (lane == 0 && bal) atomicOr(&sup[jw], bal);
      }
    }
    __syncthreads();
  }
}

// ---------------------------------------------------------------- output ----
// (fallback path only)
__global__ void output_kernel(const float* __restrict__ dx1, const float* __restrict__ dy1,
                              const float* __restrict__ dx2, const float* __restrict__ dy2,
                              const float* __restrict__ dsc,
                              const unsigned int* __restrict__ keepflag,
                              float* __restrict__ out) {
#pragma clang fp contract(off)
  int gid = blockIdx.x * blockDim.x + threadIdx.x;
  if (gid >= N_TOTAL) return;
  float f = keepflag[gid] ? 1.0f : 0.0f;
  out[gid * 5 + 0] = dx1[gid] * f;
  out[gid * 5 + 1] = dy1[gid] * f;
  out[gid * 5 + 2] = dx2[gid] * f;
  out[gid * 5 + 3] = dy2[gid] * f;
  out[gid * 5 + 4] = dsc[gid] * f;
}

// ---------------------------------------------------------------- launch ----
extern "C" void kernel_launch(void* const* d_in, const int* in_sizes, int n_in,
                              void* d_out, int out_size, void* d_ws, size_t ws_size,
                              hipStream_t stream) {
  (void)in_sizes; (void)n_in; (void)out_size;

  Inputs in;
  for (int i = 0; i < 6; ++i) {
    in.cls[i] = (const float*)d_in[2 * i];
    in.reg[i] = (const float*)d_in[2 * i + 1];
  }

  char* ws = (char*)d_ws;
  size_t o = 0;
  float* dx1 = (float*)(ws + o); o += (size_t)NA * 4;
  float* dy1 = (float*)(ws + o); o += (size_t)NA * 4;
  float* dx2 = (float*)(ws + o); o += (size_t)NA * 4;
  float* dy2 = (float*)(ws + o); o += (size_t)NA * 4;
  float* dsc = (float*)(ws + o); o += (size_t)NA * 4;
  unsigned long long* ckey = (unsigned long long*)(ws + o); o += (size_t)NA * 8;
  float* sx1 = (float*)(ws + o); o += (size_t)NA * 4;
  float* sy1 = (float*)(ws + o); o += (size_t)NA * 4;
  float* sx2 = (float*)(ws + o); o += (size_t)NA * 4;
  float* sy2 = (float*)(ws + o); o += (size_t)NA * 4;
  unsigned int* sorig = (unsigned int*)(ws + o); o += (size_t)NA * 4;
  unsigned int* keepflag = (unsigned int*)(ws + o); o += (size_t)NA * 4;
  unsigned int* rank32 = (unsigned int*)(ws + o); o += (size_t)NA * 4;
  unsigned int* wcnt = (unsigned int*)(ws + o); o += (size_t)NA * 4;
  unsigned int* Mc = (unsigned int*)(ws + o); o += 64;
  o = (o + 511) & ~(size_t)511;
  unsigned long long* diag = (unsigned long long*)(ws + o); o += (size_t)NA2 * 8;
  unsigned long long* bandT = (unsigned long long*)(ws + o); o += (size_t)NBAND * NA2 * 8;
  unsigned long long* rlBits = (unsigned long long*)(ws + o); o += (size_t)TOT_ENT * 8;
  unsigned short* rlMeta = (unsigned short*)(ws + o); o += (size_t)TOT_ENT * 2;
  size_t need = o;                            // ~40 MiB
  const bool fast = (need <= ws_size);        // ws_size constant -> graph-safe

  const int nb = (N_TOTAL + 255) / 256;  // 86

  if (fast) {
    (void)hipMemsetAsync((void*)Mc, 0, 64, stream);
    decode_kernel<<<nb, 256, 0, stream>>>(in, dx1, dy1, dx2, dy2, dsc, ckey, Mc,
                                          rank32, wcnt, (float*)d_out);
    rank_kernel<<<dim3(nb, NSLICE), 256, 0, stream>>>(ckey, Mc, dx1, dy1, dx2, dy2,
                                                      sx1, sy1, sx2, sy2, sorig,
                                                      rank32);
    pairs_kernel<<<dim3(22, W_MAX), 1024, 0, stream>>>(sx1, sy1, sx2, sy2, Mc,
                                                       diag, bandT, wcnt, rlMeta, rlBits);
    scan_kernel<<<1, SCAN_T, 0, stream>>>(diag, bandT, wcnt, rlMeta, rlBits, sorig, Mc,
                                          dx1, dy1, dx2, dy2, dsc, (float*)d_out);
  } else {
    // fallback: zero keepflag + rank32 + wcnt + Mc (contiguous)
    (void)hipMemsetAsync((void*)keepflag, 0, (size_t)NA * 12 + 64, stream);
    decode_kernel<<<nb, 256, 0, stream>>>(in, dx1, dy1, dx2, dy2, dsc, ckey, Mc,
                                          rank32, wcnt, (float*)d_out);
    rank_kernel<<<dim3(nb, NSLICE), 256, 0, stream>>>(ckey, Mc, dx1, dy1, dx2, dy2,
                                                      sx1, sy1, sx2, sy2, sorig,
                                                      rank32);
    nms_kernel<<<1, 1024, 0, stream>>>(sx1, sy1, sx2, sy2, sorig, Mc, keepflag);
    output_kernel<<<nb, 256, 0, stream>>>(dx1, dy1, dx2, dy2, dsc, keepflag,
                                          (float*)d_out);
  }
}

// Round 10
// 261.624 us; speedup vs baseline: 1.1356x; 1.1356x over previous
//
#include <hip/hip_runtime.h>
#include <stdint.h>

#define N_TOTAL 21840
#define NA      21888          // N_TOTAL rounded up to multiple of 64
#define W_MAX   342            // ceil(21840/64)
#define TOT_ENT 3753792u       // 64 * (342*343/2)  triangular dense capacity
#define NMS_TH  0.3f
#define FINAL_TH 0.5f
#define NSLICE  8              // rank range-split factor
#define SCAN_T  768            // scan block: 1 scanner wave + 11 pusher waves
#define NPUSH   11             // pusher wave count (SCAN_T/64 - 1)
#define PLANES  704            // NPUSH*64 pusher lanes
#define GRP     4              // words per scan group
#define NBAND   7              // 2*GRP-1 transposed band arrays
#define GMAX    86             // max groups = ceil(W_MAX/GRP)

struct Inputs { const float* cls[6]; const float* reg[6]; };

// Raw barrier: drains LDS (lgkmcnt) but NOT vmem (vmcnt).
__device__ __forceinline__ void block_bar() {
  asm volatile("s_waitcnt lgkmcnt(0)\n\ts_barrier" ::: "memory");
}

// Dense per-word base: word w owns 64*(342-w) entry slots (triangular).
__device__ __forceinline__ unsigned wbase_u(unsigned w) {
  return 64u * (342u * w - (w * (w - 1u)) / 2u);
}

// ---------------------------------------------------------------- decode ----
__global__ void decode_kernel(Inputs in,
                              float* __restrict__ dx1, float* __restrict__ dy1,
                              float* __restrict__ dx2, float* __restrict__ dy2,
                              float* __restrict__ dsc,
                              unsigned long long* __restrict__ ckey,
                              unsigned int* __restrict__ Mc,
                              unsigned int* __restrict__ rank32,
                              unsigned int* __restrict__ wcnt,
                              float* __restrict__ out) {
#pragma clang fp contract(off)
  int gid = blockIdx.x * blockDim.x + threadIdx.x;
  if (gid >= N_TOTAL) return;

  rank32[gid] = 0u;                       // zeroed ahead of rank_kernel
  wcnt[gid] = 0u;                         // per-word dense-entry counters
  if (gid < NA - N_TOTAL) wcnt[N_TOTAL + gid] = 0u;   // tail

  int sc, local;
  if      (gid < 16384) { sc = 0; local = gid;         }
  else if (gid < 20480) { sc = 1; local = gid - 16384; }
  else if (gid < 21504) { sc = 2; local = gid - 20480; }
  else if (gid < 21760) { sc = 3; local = gid - 21504; }
  else if (gid < 21824) { sc = 4; local = gid - 21760; }
  else                  { sc = 5; local = gid - 21824; }

  const int Wd     = 128 >> sc;
  const int stride = 4 << sc;
  const int HW     = Wd * Wd;
  const int x = local & (Wd - 1);
  const int y = local >> (7 - sc);

  const float* cls = in.cls[sc];
  const float* reg = in.reg[sc];

  float c0 = cls[local];
  float c1 = cls[HW + local];
  float m  = fmaxf(c0, c1);
  float e0 = expf(c0 - m);
  float e1 = expf(c1 - m);
  float prob = e1 / (e0 + e1);

  float l0 = reg[local];
  float l1 = reg[HW + local];
  float l2 = reg[2 * HW + local];
  float l3 = reg[3 * HW + local];

  float sF  = (float)stride;
  float pcx = 0.5f * sF + (float)x * sF;
  float pcy = 0.5f * sF + (float)y * sF;
  float pwh = sF * 4.0f;

  float cx = pcx + ((l0 * 0.1f) * pwh);
  float cy = pcy + ((l1 * 0.1f) * pwh);
  float w  = pwh * expf(l2 * 0.2f);
  float h  = pwh * expf(l3 * 0.2f);
  float x1 = cx - w * 0.5f;
  float y1 = cy - h * 0.5f;
  float x2 = x1 + w;
  float y2 = y1 + h;

  dx1[gid] = x1; dy1[gid] = y1; dx2[gid] = x2; dy2[gid] = y2; dsc[gid] = prob;

  // zero the output row; scan_kernel scatters kept rows afterwards
  out[gid * 5 + 0] = 0.0f;
  out[gid * 5 + 1] = 0.0f;
  out[gid * 5 + 2] = 0.0f;
  out[gid * 5 + 3] = 0.0f;
  out[gid * 5 + 4] = 0.0f;

  // Only boxes with score > FINAL_TH can affect the output.
  if (prob > FINAL_TH) {
    unsigned int pos = atomicAdd(Mc, 1u);
    ckey[pos] = ((unsigned long long)__float_as_uint(prob) << 32) |
                (unsigned int)(~(unsigned int)gid);
  }
}

// ---------------------------------------------------------------- rank ------
__global__ void __launch_bounds__(256)
rank_kernel(const unsigned long long* __restrict__ ckey,
            const unsigned int* __restrict__ Mc,
            const float* __restrict__ dx1, const float* __restrict__ dy1,
            const float* __restrict__ dx2, const float* __restrict__ dy2,
            float* __restrict__ sx1, float* __restrict__ sy1,
            float* __restrict__ sx2, float* __restrict__ sy2,
            unsigned int* __restrict__ sorig,
            unsigned int* __restrict__ rank32) {
  __shared__ unsigned long long tile[256];
  const unsigned int M = *Mc;
  if (blockIdx.x * 256u >= M) return;          // uniform per block
  const int t = (int)threadIdx.x;
  const int p = (int)blockIdx.x * 256 + t;
  unsigned long long mykey = (p < (int)M) ? ckey[p] : 0ull;
  const int S  = (int)((M + NSLICE - 1) / NSLICE);
  const int lo = (int)blockIdx.y * S;
  const int hi = min((int)M, lo + S);
  int partial = 0;
  const int nt = (hi > lo) ? ((hi - lo + 255) >> 8) : 0;
  for (int ti = 0; ti < nt; ++ti) {
    int j = lo + ti * 256 + t;
    tile[t] = (j < hi) ? ckey[j] : 0ull;       // 0 never > any real key
    __syncthreads();
#pragma unroll 8
    for (int q = 0; q < 256; ++q) partial += (tile[q] > mykey) ? 1 : 0;
    __syncthreads();
  }
  if (p < (int)M) {
    unsigned int pack = (unsigned int)partial | (1u << 24);
    unsigned int old  = atomicAdd(&rank32[p], pack);
    unsigned int newv = old + pack;
    if ((newv >> 24) == NSLICE) {              // last slice to land scatters
      int r = (int)(newv & 0xFFFFFF);
      unsigned int orig = ~(unsigned int)(mykey & 0xffffffffull);
      sx1[r] = dx1[orig];
      sy1[r] = dy1[orig];
      sx2[r] = dx2[orig];
      sy2[r] = dy2[orig];
      sorig[r] = orig;
    }
  }
}

// ---------------------------------------------------------------- pairs -----
// Structure for GRP=4 grouped scan:
//   diag[r]        = FULL symmetric in-word neighborhood (masked at use)
//   bandT[d-1][r]  = boxes of word (rw-d) overlapping box r, d = 1..7
//   Dense CSR      = per SOURCE WORD ranges, entry = bits + (srcLane<<9)|cw,
//                    group(cw) >= group(rw)+2 ONLY.
// Block-aggregated append (one global atomicAdd per block).
__global__ void __launch_bounds__(1024)
pairs_kernel(const float* __restrict__ sx1, const float* __restrict__ sy1,
             const float* __restrict__ sx2, const float* __restrict__ sy2,
             const unsigned int* __restrict__ Mc,
             unsigned long long* __restrict__ diag,
             unsigned long long* __restrict__ bandT,
             unsigned int* __restrict__ wcnt,
             unsigned short* __restrict__ rlMeta,
             unsigned long long* __restrict__ rlBits) {
#pragma clang fp contract(off)
  const int M = (int)*Mc;
  const int W = (M + 63) >> 6;
  const int rw = (int)blockIdx.y;
  const int cwg = (int)blockIdx.x << 4;
  if (rw >= W || cwg >= W || cwg + 22 < rw) return;   // block-uniform

  const int t = (int)threadIdx.x;
  const int g = t >> 6, l = t & 63;
  const int cw = cwg + g;

  __shared__ float cx1[1024], cy1[1024], cx2[1024], cy2[1024], car[1024];
  __shared__ unsigned wvcnt[16], wvbase[16];
  {
    int c = (cw << 6) + l;
    if (cw < W && c < M) {
      float a = sx1[c], b = sy1[c], d = sx2[c], e = sy2[c];
      cx1[t] = a; cy1[t] = b; cx2[t] = d; cy2[t] = e;
      car[t] = (d - a + 1.0f) * (e - b + 1.0f);
    }
  }
  __syncthreads();

  const int rwg = rw >> 2, cg = cw >> 2;
  const bool inW    = (cw < W);
  const bool isDiag = inW && (cw == rw);
  const bool isBand = inW && (cw < rw) && (cg >= rwg - 1);
  const bool isCsr  = inW && (cg >= rwg + 2);
  const bool any    = isDiag || isBand || isCsr;

  const int r = (rw << 6) + l;
  unsigned long long bits = 0ull;
  if (any && r < M) {
    float ax1 = sx1[r], ay1 = sy1[r], ax2 = sx2[r], ay2 = sy2[r];
    float aarea = (ax2 - ax1 + 1.0f) * (ay2 - ay1 + 1.0f);
    const int cmax = min(64, M - (cw << 6));
    const int sb = g << 6;
    for (int cc = 0; cc < cmax; ++cc) {
      float xx1 = fmaxf(ax1, cx1[sb + cc]);
      float yy1 = fmaxf(ay1, cy1[sb + cc]);
      float xx2 = fminf(ax2, cx2[sb + cc]);
      float yy2 = fminf(ay2, cy2[sb + cc]);
      float ww = fmaxf(xx2 - xx1 + 1.0f, 0.0f);
      float hh = fmaxf(yy2 - yy1 + 1.0f, 0.0f);
      float inter = ww * hh;
      float iou = inter / (aarea + car[sb + cc] - inter);
      if (iou > NMS_TH) bits |= (1ull << cc);
    }
  }
  if (isDiag)      diag[r] = bits;
  else if (isBand) bandT[(size_t)(rw - cw - 1) * NA + r] = bits;

  // CSR block-aggregated append
  unsigned long long ball = 0ull;
  unsigned myrank = 0u;
  {
    bool mine = isCsr && (bits != 0ull);
    ball = __ballot(mine);
    myrank = (unsigned)__popcll(ball & ((1ull << l) - 1ull));
    if (l == 0) wvcnt[g] = (unsigned)__popcll(ball);
  }
  __syncthreads();
  if (t == 0) {
    unsigned tot = 0u;
    unsigned pre[16];
#pragma unroll
    for (int i = 0; i < 16; ++i) { pre[i] = tot; tot += wvcnt[i]; }
    unsigned base = (tot != 0u) ? atomicAdd(&wcnt[rw], tot) : 0u;
#pragma unroll
    for (int i = 0; i < 16; ++i) wvbase[i] = base + pre[i];
  }
  __syncthreads();
  if (isCsr && bits != 0ull) {
    unsigned slot = wbase_u((unsigned)rw) + wvbase[g] + myrank;
    rlMeta[slot] = (unsigned short)(((unsigned)l << 9) | (unsigned)cw);
    rlBits[slot] = bits;
  }
}

// ---------------------------------------------------------------- scan ------
// Decoupled scan (sflag / per-group gdone protocol, verified R4/R6), GRP=4.
// R7 post-mortem: per-STEP cost is invariant at 2.31 µs across GRP=4 (99/43)
// and GRP=3 (132/57), and VGPR_Count DROPPED to 52 when state shrank —
// proof the register allocator is targeting DEFAULT occupancy (8+ waves/EU)
// and demoting every prefetch buffer to L2 reloads at use. This kernel runs
// exactly ONE 768-thread block = 3 waves/EU; occupancy above that is
// impossible. __launch_bounds__(SCAN_T, 3) declares that, raising the VGPR
// budget to 512/3 ≈ 170 so the GRP=4 ping-pong buffers (~130 VGPR) can
// genuinely live in registers. Single-variable A/B vs R6: only this changed.
// (Protocol deadlock-freedom is codegen-independent: scanner's gate at step s
// is on gdone[s-2], published by pushers after consuming sflag=s-1, which the
// scanner published unconditionally at step s-1 — no cycle at any timing.)
__global__ void __launch_bounds__(SCAN_T, 3)
scan_kernel(const unsigned long long* __restrict__ diag,
            const unsigned long long* __restrict__ bandT,
            const unsigned int* __restrict__ wcnt,
            const unsigned short* __restrict__ rlMeta,
            const unsigned long long* __restrict__ rlBits,
            const unsigned int* __restrict__ sorig,
            const unsigned int* __restrict__ Mc,
            const float* __restrict__ dx1, const float* __restrict__ dy1,
            const float* __restrict__ dx2, const float* __restrict__ dy2,
            const float* __restrict__ dsc,
            float* __restrict__ out) {
  __shared__ unsigned long long sup[W_MAX];
  __shared__ unsigned long long kmls[W_MAX];
  __shared__ unsigned lds_wcnt[W_MAX];  // per-word entry counts (staged once)
  __shared__ unsigned gdone[GMAX];      // per-group pusher completions
  __shared__ volatile unsigned sflag;   // groups published by scanner
  const int t = (int)threadIdx.x;
  const int g = t >> 6, l = t & 63;
  const int M = (int)*Mc;
  const int W = (M + 63) >> 6;
  const int NS = (W + 3) >> 2;

  for (int i = t; i < W_MAX; i += SCAN_T) {
    sup[i] = 0ull; kmls[i] = 0ull; lds_wcnt[i] = wcnt[i];
  }
  for (int i = t; i < GMAX; i += SCAN_T) gdone[i] = 0u;
  if (t == 0) sflag = 0u;
  block_bar();

  if (g == 0) {
    // -------- scanner wave (critical path) --------
    __builtin_amdgcn_s_setprio(1);
    const unsigned long long lowm = (1ull << l) - 1ull;
    unsigned long long dc[4], dn[4];                 // diag, cur / next group
    unsigned long long bc[4][NBAND], bn[4][NBAND];   // bands (d<=i+4 only)
    unsigned long long kp[4] = {0ull, 0ull, 0ull, 0ull};
#pragma unroll
    for (int i = 0; i < 4; ++i) {
      int v = i, vc = (v < W) ? v : 0;
      dc[i] = diag[(vc << 6) + l];
#pragma unroll
      for (int d = 1; d <= NBAND; ++d)
        if (d <= i + 4) bc[i][d - 1] = bandT[(size_t)(d - 1) * NA + (vc << 6) + l];
    }
#pragma unroll
    for (int i = 0; i < 4; ++i) {
      int v = 4 + i, vc = (v < W) ? v : 0;
      dn[i] = diag[(vc << 6) + l];
#pragma unroll
      for (int d = 1; d <= NBAND; ++d)
        if (d <= i + 4) bn[i][d - 1] = bandT[(size_t)(d - 1) * NA + (vc << 6) + l];
    }
    for (int s = 0; s < NS; ++s) {
      const int v0 = s << 2;
      // hoist prev-group incoming accumulators (independent of sup / kc)
      unsigned long long accp[4];
#pragma unroll
      for (int i = 0; i < 4; ++i) {
        unsigned long long a = 0ull;
#pragma unroll
        for (int d = 1; d <= NBAND; ++d)
          if (d <= i + 4 && d > i) a |= (bc[i][d - 1] & kp[i - d + 4]);
        accp[i] = a;
      }
      // gate: EVERY wave has applied all source groups <= s-2 (exact)
      if (s >= 2) {
        while (*(volatile unsigned*)&gdone[s - 2] < (unsigned)NPUSH) {}
        asm volatile("" ::: "memory");
      }
      unsigned long long sv[4];
#pragma unroll
      for (int i = 0; i < 4; ++i)
        sv[i] = (v0 + i < W) ? sup[v0 + i] : 0ull;
      unsigned long long kc[4];
#pragma unroll
      for (int i = 0; i < 4; ++i) {
        const int v = v0 + i;
        unsigned long long kept = 0ull;
        if (v < W) {
          unsigned long long acc = accp[i];
#pragma unroll
          for (int d = 1; d <= 3; ++d)
            if (d <= i) acc |= (bc[i][d - 1] & kc[i - d]);
          unsigned long long incoming = __ballot(acc != 0ull);
          const int n = min(64, M - (v << 6));
          unsigned long long wm = (n >= 64) ? ~0ull : ((1ull << n) - 1ull);
          unsigned long long pend = (~(sv[i] | incoming)) & wm;
          // ballot fixed-point: lowest undecided lane always decides
          const unsigned long long dv = dc[i] & lowm;
          unsigned long long dead = ~pend, und = pend;
          while (und) {
            unsigned long long bS = __ballot((dv & kept) != 0ull) & und;
            unsigned long long bK = __ballot((dv & ~dead) == 0ull) & und;
            kept |= bK; dead |= bS; und &= ~(bK | bS);
          }
          if (l == i) kmls[v] = kept;
        }
        kc[i] = kept;
      }
      // publish group s (kmls writes drained first; wave-level lgkmcnt)
      asm volatile("s_waitcnt lgkmcnt(0)" ::: "memory");
      if (l == 0) sflag = (unsigned)(s + 1);
      // rotate pipelines; issue loads for group s+2
#pragma unroll
      for (int i = 0; i < 4; ++i) kp[i] = kc[i];
#pragma unroll
      for (int i = 0; i < 4; ++i) {
        dc[i] = dn[i];
#pragma unroll
        for (int d = 0; d < NBAND; ++d)
          if (d <= i + 3) bc[i][d] = bn[i][d];
      }
      const int vn = v0 + 8;
#pragma unroll
      for (int i = 0; i < 4; ++i) {
        int v = vn + i, vc = (v < W) ? v : 0;
        dn[i] = diag[(vc << 6) + l];
#pragma unroll
        for (int d = 1; d <= NBAND; ++d)
          if (d <= i + 4) bn[i][d - 1] = bandT[(size_t)(d - 1) * NA + (vc << 6) + l];
      }
    }
    __builtin_amdgcn_s_setprio(0);
  } else {
    // -------- pusher lanes: dense ranges, static-address depth-2 pipeline --
    const int p = (g - 1) * 64 + l;              // 0..703

#define PUSH_LOAD(mX, bX, gs)                                               \
    {                                                                       \
      _Pragma("unroll")                                                     \
      for (int i = 0; i < 4; ++i) {                                         \
        int v = (gs) * 4 + i;                                               \
        unsigned vc = (v < W) ? (unsigned)v : 0u;                           \
        unsigned base = wbase_u(vc);                                        \
        unsigned i0 = base + (unsigned)p;   if (i0 >= TOT_ENT) i0 = 0u;     \
        unsigned i1 = i0 + (unsigned)PLANES; if (i1 >= TOT_ENT) i1 = 0u;    \
        mX[i][0] = (unsigned)rlMeta[i0]; bX[i][0] = rlBits[i0];             \
        mX[i][1] = (unsigned)rlMeta[i1]; bX[i][1] = rlBits[i1];             \
      }                                                                     \
    }

    unsigned mA[4][2], mB[4][2];
    unsigned long long bA[4][2], bB[4][2];
    PUSH_LOAD(mA, bA, 0)
    PUSH_LOAD(mB, bB, 1)
    for (int s = 0; s < NS; ++s) {
      // wait for scanner to publish group s (sleep: don't steal issue slots)
      while (sflag < (unsigned)(s + 1)) __builtin_amdgcn_s_sleep(1);
      asm volatile("" ::: "memory");
#pragma unroll
      for (int i = 0; i < 4; ++i) {
        const int v = (s << 2) + i;
        if (v < W) {
          const unsigned tw = lds_wcnt[v];
          const unsigned long long km = kmls[v];
          if (km != 0ull && tw != 0u) {
            if ((unsigned)p < tw && ((km >> (mA[i][0] >> 9)) & 1ull))
              atomicOr(&sup[mA[i][0] & 511u], bA[i][0]);
            if ((unsigned)p + (unsigned)PLANES < tw &&
                ((km >> (mA[i][1] >> 9)) & 1ull))
              atomicOr(&sup[mA[i][1] & 511u], bA[i][1]);
            if (tw > 2u * (unsigned)PLANES) {    // rare overflow tail
              unsigned base = wbase_u((unsigned)v);
              for (unsigned ii = (unsigned)p + 2u * (unsigned)PLANES;
                   ii < tw; ii += (unsigned)PLANES) {
                unsigned sl = base + ii; if (sl >= TOT_ENT) sl = TOT_ENT - 1u;
                unsigned mm = (unsigned)rlMeta[sl];
                if ((km >> (mm >> 9)) & 1ull)
                  atomicOr(&sup[mm & 511u], rlBits[sl]);
              }
            }
          }
        }
      }
      // publish completion of source group s (sup atomics drained first)
      asm volatile("s_waitcnt lgkmcnt(0)" ::: "memory");
      if (l == 0) atomicAdd(&gdone[s], 1u);
      // rotate A <- B; issue loads for group s+2 (static addresses)
#pragma unroll
      for (int i = 0; i < 4; ++i) {
        mA[i][0] = mB[i][0]; mA[i][1] = mB[i][1];
        bA[i][0] = bB[i][0]; bA[i][1] = bB[i][1];
      }
      PUSH_LOAD(mB, bB, s + 2)
    }
#undef PUSH_LOAD
  }
  block_bar();

  // scatter kept rows into the (pre-zeroed) output
  for (int i = t; i < (W << 6); i += SCAN_T) {
    if ((kmls[i >> 6] >> (i & 63)) & 1ull) {
      unsigned int orig = sorig[i];
      out[(size_t)orig * 5 + 0] = dx1[orig];
      out[(size_t)orig * 5 + 1] = dy1[orig];
      out[(size_t)orig * 5 + 2] = dx2[orig];
      out[(size_t)orig * 5 + 3] = dy2[orig];
      out[(size_t)orig * 5 + 4] = dsc[orig];
    }
  }
}

// ------------------------------------------------- fallback NMS (tiny ws) ---
__global__ void __launch_bounds__(1024)
nms_kernel(const float* __restrict__ sx1, const float* __restrict__ sy1,
           const float* __restrict__ sx2, const float* __restrict__ sy2,
           const unsigned int* __restrict__ sorig,
           const unsigned int* __restrict__ Mc,
           unsigned int* __restrict__ keepflag) {
#pragma clang fp contract(off)
  __shared__ unsigned long long sup[W_MAX];
  __shared__ unsigned long long inrow[64];
  __shared__ float wx1[64], wy1[64], wx2[64], wy2[64], warea[64];
  __shared__ unsigned long long keptmask_sh;

  const int t = (int)threadIdx.x;
  const int M = (int)*Mc;
  const int W = (M + 63) >> 6;

  for (int i = t; i < W_MAX; i += 1024) sup[i] = 0ull;
  __syncthreads();

  for (int w = 0; w < W; ++w) {
    const int base = w << 6;
    const int n = min(64, M - base);
    if (t < 64) {
      if (t < n) {
        float a = sx1[base + t], b = sy1[base + t];
        float c = sx2[base + t], d = sy2[base + t];
        wx1[t] = a; wy1[t] = b; wx2[t] = c; wy2[t] = d;
        warea[t] = (c - a + 1.0f) * (d - b + 1.0f);
      }
    } else if (t < 128) {
      inrow[t - 64] = 0ull;
    }
    __syncthreads();
    {
      int r = t & 63, seg = t >> 6;
      unsigned long long bits = 0ull;
      if (r < n) {
        float ax1 = wx1[r], ay1 = wy1[r], ax2 = wx2[r], ay2 = wy2[r];
        float aarea = warea[r];
        for (int c = seg * 4; c < seg * 4 + 4; ++c) {
          if (c > r && c < n) {
            float xx1 = fmaxf(ax1, wx1[c]);
            float yy1 = fmaxf(ay1, wy1[c]);
            float xx2 = fminf(ax2, wx2[c]);
            float yy2 = fminf(ay2, wy2[c]);
            float ww = fmaxf(xx2 - xx1 + 1.0f, 0.0f);
            float hh = fmaxf(yy2 - yy1 + 1.0f, 0.0f);
            float inter = ww * hh;
            float iou = inter / (aarea + warea[c] - inter);
            if (iou > NMS_TH) bits |= (1ull << c);
          }
        }
      }
      if (bits) atomicOr(&inrow[r], bits);
    }
    __syncthreads();
    if (t < 64) {
      unsigned long long wordmask = (n >= 64) ? ~0ull : ((1ull << n) - 1ull);
      unsigned long long pending = (~sup[w]) & wordmask;
      unsigned long long kept = 0ull;
      while (pending) {
        int i = __builtin_ctzll(pending);
        kept |= (1ull << i);
        pending &= ~(inrow[i] | (1ull << i));
      }
      if (t == 0) keptmask_sh = kept;
      if (t < n && ((kept >> t) & 1ull)) keepflag[sorig[base + t]] = 1u;
    }
    __syncthreads();
    unsigned long long km = keptmask_sh;
    if (km) {
      int wid = t >> 6, lane = t & 63;
      for (int jw = w + 1 + wid; (jw << 6) < M; jw += 16) {
        int j = (jw << 6) + lane;
        bool supj = false;
        if (j < M) {
          float jx1 = sx1[j], jy1 = sy1[j], jx2 = sx2[j], jy2 = sy2[j];
          float jarea = (jx2 - jx1 + 1.0f) * (jy2 - jy1 + 1.0f);
          unsigned long long mm = km;
          while (mm) {
            int r = __builtin_ctzll(mm);
            mm &= mm - 1ull;
            float xx1 = fmaxf(wx1[r], jx1);
            float yy1 = fmaxf(wy1[r], jy1);
            float xx2 = fminf(wx2[r], jx2);
            float yy2 = fminf(wy2[r], jy2);
            float ww = fmaxf(xx2 - xx1 + 1.0f, 0.0f);
            float hh = fmaxf(yy2 - yy1 + 1.0f, 0.0f);
            float inter = ww * hh;
            float iou = inter / (warea[r] + jarea - inter);
            if (iou > NMS_TH) { supj = true; break; }
          }
        }
        unsigned long long bal = __ballot(supj);
        if (lane == 0 && bal) atomicOr(&sup[jw], bal);
      }
    }
    __syncthreads();
  }
}

// ---------------------------------------------------------------- output ----
// (fallback path only)
__global__ void output_kernel(const float* __restrict__ dx1, const float* __restrict__ dy1,
                              const float* __restrict__ dx2, const float* __restrict__ dy2,
                              const float* __restrict__ dsc,
                              const unsigned int* __restrict__ keepflag,
                              float* __restrict__ out) {
#pragma clang fp contract(off)
  int gid = blockIdx.x * blockDim.x + threadIdx.x;
  if (gid >= N_TOTAL) return;
  float f = keepflag[gid] ? 1.0f : 0.0f;
  out[gid * 5 + 0] = dx1[gid] * f;
  out[gid * 5 + 1] = dy1[gid] * f;
  out[gid * 5 + 2] = dx2[gid] * f;
  out[gid * 5 + 3] = dy2[gid] * f;
  out[gid * 5 + 4] = dsc[gid] * f;
}

// ---------------------------------------------------------------- launch ----
extern "C" void kernel_launch(void* const* d_in, const int* in_sizes, int n_in,
                              void* d_out, int out_size, void* d_ws, size_t ws_size,
                              hipStream_t stream) {
  (void)in_sizes; (void)n_in; (void)out_size;

  Inputs in;
  for (int i = 0; i < 6; ++i) {
    in.cls[i] = (const float*)d_in[2 * i];
    in.reg[i] = (const float*)d_in[2 * i + 1];
  }

  char* ws = (char*)d_ws;
  size_t o = 0;
  float* dx1 = (float*)(ws + o); o += (size_t)NA * 4;
  float* dy1 = (float*)(ws + o); o += (size_t)NA * 4;
  float* dx2 = (float*)(ws + o); o += (size_t)NA * 4;
  float* dy2 = (float*)(ws + o); o += (size_t)NA * 4;
  float* dsc = (float*)(ws + o); o += (size_t)NA * 4;
  unsigned long long* ckey = (unsigned long long*)(ws + o); o += (size_t)NA * 8;
  float* sx1 = (float*)(ws + o); o += (size_t)NA * 4;
  float* sy1 = (float*)(ws + o); o += (size_t)NA * 4;
  float* sx2 = (float*)(ws + o); o += (size_t)NA * 4;
  float* sy2 = (float*)(ws + o); o += (size_t)NA * 4;
  unsigned int* sorig = (unsigned int*)(ws + o); o += (size_t)NA * 4;
  unsigned int* keepflag = (unsigned int*)(ws + o); o += (size_t)NA * 4;
  unsigned int* rank32 = (unsigned int*)(ws + o); o += (size_t)NA * 4;
  unsigned int* wcnt = (unsigned int*)(ws + o); o += (size_t)NA * 4;
  unsigned int* Mc = (unsigned int*)(ws + o); o += 64;
  o = (o + 511) & ~(size_t)511;
  unsigned long long* diag = (unsigned long long*)(ws + o); o += (size_t)NA * 8;
  unsigned long long* bandT = (unsigned long long*)(ws + o); o += (size_t)NBAND * NA * 8;
  unsigned long long* rlBits = (unsigned long long*)(ws + o); o += (size_t)TOT_ENT * 8;
  unsigned short* rlMeta = (unsigned short*)(ws + o); o += (size_t)TOT_ENT * 2;
  size_t need = o;                            // ~41 MiB
  const bool fast = (need <= ws_size);        // ws_size constant -> graph-safe

  const int nb = (N_TOTAL + 255) / 256;  // 86

  if (fast) {
    (void)hipMemsetAsync((void*)Mc, 0, 64, stream);
    decode_kernel<<<nb, 256, 0, stream>>>(in, dx1, dy1, dx2, dy2, dsc, ckey, Mc,
                                          rank32, wcnt, (float*)d_out);
    rank_kernel<<<dim3(nb, NSLICE), 256, 0, stream>>>(ckey, Mc, dx1, dy1, dx2, dy2,
                                                      sx1, sy1, sx2, sy2, sorig,
                                                      rank32);
    pairs_kernel<<<dim3(22, W_MAX), 1024, 0, stream>>>(sx1, sy1, sx2, sy2, Mc,
                                                       diag, bandT, wcnt, rlMeta, rlBits);
    scan_kernel<<<1, SCAN_T, 0, stream>>>(diag, bandT, wcnt, rlMeta, rlBits, sorig, Mc,
                                          dx1, dy1, dx2, dy2, dsc, (float*)d_out);
  } else {
    // fallback: zero keepflag + rank32 + wcnt + Mc (contiguous)
    (void)hipMemsetAsync((void*)keepflag, 0, (size_t)NA * 12 + 64, stream);
    decode_kernel<<<nb, 256, 0, stream>>>(in, dx1, dy1, dx2, dy2, dsc, ckey, Mc,
                                          rank32, wcnt, (float*)d_out);
    rank_kernel<<<dim3(nb, NSLICE), 256, 0, stream>>>(ckey, Mc, dx1, dy1, dx2, dy2,
                                                      sx1, sy1, sx2, sy2, sorig,
                                                      rank32);
    nms_kernel<<<1, 1024, 0, stream>>>(sx1, sy1, sx2, sy2, sorig, Mc, keepflag);
    output_kernel<<<nb, 256, 0, stream>>>(dx1, dy1, dx2, dy2, dsc, keepflag,
                                          (float*)d_out);
  }
}